// Round 4
// baseline (243.980 us; speedup 1.0000x reference)
//
#include <hip/hip_runtime.h>
#include <float.h>

#define D 64
#define K 512
#define HW 1024
#define DHW (D * HW)
#define N_PTS 65536
#define OUT_ELEMS (64 * D * HW)     /* 4,194,304 */
#define LOSS_OFF OUT_ELEMS
#define IDX_OFF (OUT_ELEMS + 1)
#define PTS_PER_BLOCK 64
#define NBLOCKS (N_PTS / PTS_PER_BLOCK)   /* 1024 */

// ---------------------------------------------------------------------------
// numpy pairwise-sum (n=64) replication helper: 8 accumulators over squares,
// combined ((r0+r1)+(r2+r3))+((r4+r5)+(r6+r7)), all adds/muls un-contracted.
// ---------------------------------------------------------------------------
__device__ __forceinline__ float np_sumsq64(const float* v) {
    float r[8];
#pragma unroll
    for (int j = 0; j < 8; ++j) r[j] = __fmul_rn(v[j], v[j]);
#pragma unroll
    for (int i = 8; i < D; i += 8) {
#pragma unroll
        for (int j = 0; j < 8; ++j)
            r[j] = __fadd_rn(r[j], __fmul_rn(v[i + j], v[i + j]));
    }
    return __fadd_rn(
        __fadd_rn(__fadd_rn(r[0], r[1]), __fadd_rn(r[2], r[3])),
        __fadd_rn(__fadd_rn(r[4], r[5]), __fadd_rn(r[6], r[7])));
}

// ---------------------------------------------------------------------------
// Kernel 1: ||e_k||^2 in numpy pairwise order -> ws
// ---------------------------------------------------------------------------
__global__ void vq_e2_kernel(const float* __restrict__ cb,
                             float* __restrict__ e2) {
    int k = blockIdx.x * blockDim.x + threadIdx.x;
    if (k < K) {
        float row[D];
#pragma unroll
        for (int d = 0; d < D; ++d) row[d] = cb[k * D + d];
        e2[k] = np_sumsq64(row);
    }
}

// ---------------------------------------------------------------------------
// Kernel 2: main VQ, restructured (round-3 post-mortem: per-lane x[64] array
// never stays in VGPRs — VGPR_Count pinned at 56, K-loop ran off-register).
// Now: block = 4 waves = 64 points. x staged in LDS [d][point]; wave w scans
// codes [128w,128w+128) for all 64 points (point = lane). Per-lane live state
// is 8 accumulators -> ~32 VGPRs, 4 waves/SIMD, nothing can spill.
// ---------------------------------------------------------------------------
__global__ __launch_bounds__(256, 4) void vq_main_kernel(
        const float* __restrict__ z, const float* __restrict__ cb,
        const float* __restrict__ e2, float* __restrict__ out,
        float* __restrict__ partial) {
    __shared__ float x_lds[D][PTS_PER_BLOCK];     // 16 KB, [d][point]
    __shared__ float bestd_l[4][PTS_PER_BLOCK];
    __shared__ int   besti_l[4][PTS_PER_BLOCK];
    __shared__ int   ids[PTS_PER_BLOCK];
    __shared__ float wsum[4];

    const int lane = threadIdx.x & 63;
    const int w    = threadIdx.x >> 6;
    const int n0   = blockIdx.x * PTS_PER_BLOCK;  // 64 consecutive points
    const int b    = n0 >> 10;                    // one image per block
    const int hw0  = n0 & 1023;

    // Phase 1: stage x, coalesced global -> LDS (wave w loads d = 16w..16w+15)
    const float* zb = z + b * DHW + hw0;
#pragma unroll
    for (int i = 0; i < 16; ++i) {
        const int d = w * 16 + i;
        x_lds[d][lane] = zb[d * HW + lane];
    }
    __syncthreads();

    // A = numpy pairwise ||x||^2 for point `lane` (streaming, 8 accumulators
    // in the same grouping/combine order as np_sumsq64).
    float r[8];
#pragma unroll
    for (int j = 0; j < 8; ++j) {
        float v = x_lds[j][lane];
        r[j] = __fmul_rn(v, v);
    }
#pragma unroll
    for (int d = 8; d < D; ++d) {
        float v = x_lds[d][lane];
        r[d & 7] = __fadd_rn(r[d & 7], __fmul_rn(v, v));
    }
    const float A = __fadd_rn(
        __fadd_rn(__fadd_rn(r[0], r[1]), __fadd_rn(r[2], r[3])),
        __fadd_rn(__fadd_rn(r[4], r[5]), __fadd_rn(r[6], r[7])));

    // Phase 2: wave w scans its 128 codes; 8-code batches, 8 FMA chains.
    // dist = fl( fl(A + ||e||^2) - fl(2*M) ) — bit-identical to numpy's
    // rounding pipeline so quantized ties resolve identically.
    const int kbase = w * 128;
    float best = FLT_MAX;
    int   bidx = 0;
    for (int kk = 0; kk < 128; kk += 8) {
        float acc[8];
#pragma unroll
        for (int j = 0; j < 8; ++j) acc[j] = 0.f;
#pragma unroll
        for (int d = 0; d < D; ++d) {
            const float xd = x_lds[d][lane];          // 1 ds_read feeds 8 FMAs
#pragma unroll
            for (int j = 0; j < 8; ++j)               // cb operand wave-uniform
                acc[j] = __builtin_fmaf(xd, cb[(kbase + kk + j) * D + d], acc[j]);
        }
#pragma unroll
        for (int j = 0; j < 8; ++j) {
            float dist = __fsub_rn(__fadd_rn(A, e2[kbase + kk + j]),
                                   2.0f * acc[j]);
            if (dist < best) { best = dist; bidx = kbase + kk + j; }
        }
    }
    bestd_l[w][lane] = best;
    besti_l[w][lane] = bidx;
    __syncthreads();

    // Phase 3: merge the 4 waves' candidates. Ascending wave order + strict <
    // keeps the lowest index on exact (quantized) ties — numpy argmin rule.
    if (w == 0) {
        float fb = bestd_l[0][lane];
        int   fi = besti_l[0][lane];
#pragma unroll
        for (int ww = 1; ww < 4; ++ww) {
            float dw = bestd_l[ww][lane];
            int   iw = besti_l[ww][lane];
            if (dw < fb) { fb = dw; fi = iw; }
        }
        ids[lane] = fi;
        out[IDX_OFF + n0 + lane] = (float)fi;   // idx as float in f32 buffer
    }
    __syncthreads();

    // Phase 4: epilogue — out = fl(x + fl(q - x)) (straight-through), loss.
    float* ob = out + b * DHW + hw0;
    const int myid = ids[lane];
    float lsum = 0.f;
#pragma unroll
    for (int i = 0; i < 16; ++i) {
        const int d  = w * 16 + i;
        const float xv   = x_lds[d][lane];
        const float q    = cb[myid * D + d];       // gather, codebook L1/L2-hot
        const float diff = __fsub_rn(q, xv);
        lsum = __builtin_fmaf(diff, diff, lsum);
        ob[d * HW + lane] = __fadd_rn(xv, diff);   // coalesced store
    }

    // Deterministic loss partials: wave shuffle reduce -> LDS -> per-block.
#pragma unroll
    for (int off = 32; off > 0; off >>= 1) lsum += __shfl_down(lsum, off);
    if (lane == 0) wsum[w] = lsum;
    __syncthreads();
    if (threadIdx.x == 0)
        partial[blockIdx.x] = __fadd_rn(__fadd_rn(wsum[0], wsum[1]),
                                        __fadd_rn(wsum[2], wsum[3]));
}

// ---------------------------------------------------------------------------
// Kernel 3: reduce 1024 block partials -> loss = 1.25 * MSE
// ---------------------------------------------------------------------------
__global__ void vq_loss_kernel(const float* __restrict__ partial,
                               float* __restrict__ out) {
    __shared__ float sh[256];
    float s = 0.f;
#pragma unroll
    for (int i = 0; i < NBLOCKS / 256; ++i)
        s += partial[threadIdx.x + i * 256];
    sh[threadIdx.x] = s;
    __syncthreads();
    for (int off = 128; off > 0; off >>= 1) {
        if (threadIdx.x < off) sh[threadIdx.x] += sh[threadIdx.x + off];
        __syncthreads();
    }
    if (threadIdx.x == 0)
        out[LOSS_OFF] = 1.25f * sh[0] / (float)OUT_ELEMS;
}

extern "C" void kernel_launch(void* const* d_in, const int* in_sizes, int n_in,
                              void* d_out, int out_size, void* d_ws,
                              size_t ws_size, hipStream_t stream) {
    const float* z  = (const float*)d_in[0];   // [64, 64, 32, 32] f32
    const float* cb = (const float*)d_in[1];   // [512, 64] f32
    float* out = (float*)d_out;
    float* wsf = (float*)d_ws;
    float* e2      = wsf;          // 512 floats
    float* partial = wsf + K;      // 1024 floats

    vq_e2_kernel<<<(K + 255) / 256, 256, 0, stream>>>(cb, e2);
    vq_main_kernel<<<NBLOCKS, 256, 0, stream>>>(z, cb, e2, out, partial);
    vq_loss_kernel<<<1, 256, 0, stream>>>(partial, out);
}

// Round 5
// 97.426 us; speedup vs baseline: 2.5043x; 2.5043x over previous
//
#include <hip/hip_runtime.h>
#include <float.h>

#define D 64
#define K 512
#define HW 1024
#define DHW (D * HW)
#define N_PTS 65536
#define OUT_ELEMS (64 * D * HW)     /* 4,194,304 */
#define LOSS_OFF OUT_ELEMS
#define IDX_OFF (OUT_ELEMS + 1)
#define PTS_PER_BLOCK 64
#define NBLOCKS (N_PTS / PTS_PER_BLOCK)   /* 1024 */

// ---------------------------------------------------------------------------
// numpy pairwise-sum (n=64) replication helper: 8 accumulators over squares,
// combined ((r0+r1)+(r2+r3))+((r4+r5)+(r6+r7)), all adds/muls un-contracted.
// ---------------------------------------------------------------------------
__device__ __forceinline__ float np_sumsq64(const float* v) {
    float r[8];
#pragma unroll
    for (int j = 0; j < 8; ++j) r[j] = __fmul_rn(v[j], v[j]);
#pragma unroll
    for (int i = 8; i < D; i += 8) {
#pragma unroll
        for (int j = 0; j < 8; ++j)
            r[j] = __fadd_rn(r[j], __fmul_rn(v[i + j], v[i + j]));
    }
    return __fadd_rn(
        __fadd_rn(__fadd_rn(r[0], r[1]), __fadd_rn(r[2], r[3])),
        __fadd_rn(__fadd_rn(r[4], r[5]), __fadd_rn(r[6], r[7])));
}

// ---------------------------------------------------------------------------
// Kernel 1: ||e_k||^2 in numpy pairwise order -> ws
// ---------------------------------------------------------------------------
__global__ void vq_e2_kernel(const float* __restrict__ cb,
                             float* __restrict__ e2) {
    int k = blockIdx.x * blockDim.x + threadIdx.x;
    if (k < K) {
        float row[D];
#pragma unroll
        for (int d = 0; d < D; ++d) row[d] = cb[k * D + d];
        e2[k] = np_sumsq64(row);
    }
}

// ---------------------------------------------------------------------------
// Kernel 2: main VQ. Block = 4 waves = 64 points; x staged in LDS [d][point];
// wave w scans codes [128w, 128w+128).
//
// Round-4 post-mortem: kbase = w*128 (threadIdx-derived) defeated the
// compiler's uniformity analysis -> cb reads became per-lane global_load
// broadcasts (SGPR_Count fell 112->32, VALUBusy 22%). readfirstlane puts
// kbase in an SGPR, making cb addresses provably scalar -> s_load chains on
// the SMEM pipe, VALU free to stream FMAs (floor ~27 us).
// ---------------------------------------------------------------------------
__global__ __launch_bounds__(256, 4) void vq_main_kernel(
        const float* __restrict__ z, const float* __restrict__ cb,
        const float* __restrict__ e2, float* __restrict__ out,
        float* __restrict__ partial) {
    __shared__ float x_lds[D][PTS_PER_BLOCK];     // 16 KB, [d][point]
    __shared__ float bestd_l[4][PTS_PER_BLOCK];
    __shared__ int   besti_l[4][PTS_PER_BLOCK];
    __shared__ int   ids[PTS_PER_BLOCK];
    __shared__ float wsum[4];

    const int lane = threadIdx.x & 63;
    const int w    = threadIdx.x >> 6;
    const int n0   = blockIdx.x * PTS_PER_BLOCK;  // 64 consecutive points
    const int b    = n0 >> 10;                    // one image per block
    const int hw0  = n0 & 1023;

    // Phase 1: stage x, coalesced global -> LDS (wave w loads d = 16w..16w+15)
    const float* zb = z + b * DHW + hw0;
#pragma unroll
    for (int i = 0; i < 16; ++i) {
        const int d = w * 16 + i;
        x_lds[d][lane] = zb[d * HW + lane];
    }
    __syncthreads();

    // A = numpy pairwise ||x||^2 for point `lane` (streaming, 8 accumulators
    // in the same grouping/combine order as np_sumsq64).
    float r[8];
#pragma unroll
    for (int j = 0; j < 8; ++j) {
        float v = x_lds[j][lane];
        r[j] = __fmul_rn(v, v);
    }
#pragma unroll
    for (int d = 8; d < D; ++d) {
        float v = x_lds[d][lane];
        r[d & 7] = __fadd_rn(r[d & 7], __fmul_rn(v, v));
    }
    const float A = __fadd_rn(
        __fadd_rn(__fadd_rn(r[0], r[1]), __fadd_rn(r[2], r[3])),
        __fadd_rn(__fadd_rn(r[4], r[5]), __fadd_rn(r[6], r[7])));

    // Phase 2: wave w scans its 128 codes; 8-code batches, 8 FMA chains.
    // kbase via readfirstlane => SGPR => cb/e2 addresses provably uniform.
    const int kbase = __builtin_amdgcn_readfirstlane(w) * 128;
    float best = FLT_MAX;
    int   bidx = 0;
    for (int kk = 0; kk < 128; kk += 8) {
        float acc[8];
#pragma unroll
        for (int j = 0; j < 8; ++j) acc[j] = 0.f;
#pragma unroll
        for (int d = 0; d < D; ++d) {
            const float xd = x_lds[d][lane];          // 1 ds_read feeds 8 FMAs
#pragma unroll
            for (int j = 0; j < 8; ++j)               // cb operand: s_load (SGPR)
                acc[j] = __builtin_fmaf(xd, cb[(kbase + kk + j) * D + d], acc[j]);
        }
#pragma unroll
        for (int j = 0; j < 8; ++j) {
            // dist = fl( fl(A + ||e||^2) - fl(2*M) ) — numpy's rounding
            // pipeline, so quantized ties resolve identically.
            float dist = __fsub_rn(__fadd_rn(A, e2[kbase + kk + j]),
                                   2.0f * acc[j]);
            if (dist < best) { best = dist; bidx = kbase + kk + j; }
        }
    }
    bestd_l[w][lane] = best;
    besti_l[w][lane] = bidx;
    __syncthreads();

    // Phase 3: merge the 4 waves' candidates. Ascending wave order + strict <
    // keeps the lowest index on exact (quantized) ties — numpy argmin rule.
    if (w == 0) {
        float fb = bestd_l[0][lane];
        int   fi = besti_l[0][lane];
#pragma unroll
        for (int ww = 1; ww < 4; ++ww) {
            float dw = bestd_l[ww][lane];
            int   iw = besti_l[ww][lane];
            if (dw < fb) { fb = dw; fi = iw; }
        }
        ids[lane] = fi;
        out[IDX_OFF + n0 + lane] = (float)fi;   // idx as float in f32 buffer
    }
    __syncthreads();

    // Phase 4: epilogue — out = fl(x + fl(q - x)) (straight-through), loss.
    float* ob = out + b * DHW + hw0;
    const int myid = ids[lane];
    float lsum = 0.f;
#pragma unroll
    for (int i = 0; i < 16; ++i) {
        const int d  = w * 16 + i;
        const float xv   = x_lds[d][lane];
        const float q    = cb[myid * D + d];       // gather, codebook L1/L2-hot
        const float diff = __fsub_rn(q, xv);
        lsum = __builtin_fmaf(diff, diff, lsum);
        ob[d * HW + lane] = __fadd_rn(xv, diff);   // coalesced store
    }

    // Deterministic loss partials: wave shuffle reduce -> LDS -> per-block.
#pragma unroll
    for (int off = 32; off > 0; off >>= 1) lsum += __shfl_down(lsum, off);
    if (lane == 0) wsum[w] = lsum;
    __syncthreads();
    if (threadIdx.x == 0)
        partial[blockIdx.x] = __fadd_rn(__fadd_rn(wsum[0], wsum[1]),
                                        __fadd_rn(wsum[2], wsum[3]));
}

// ---------------------------------------------------------------------------
// Kernel 3: reduce 1024 block partials -> loss = 1.25 * MSE
// ---------------------------------------------------------------------------
__global__ void vq_loss_kernel(const float* __restrict__ partial,
                               float* __restrict__ out) {
    __shared__ float sh[256];
    float s = 0.f;
#pragma unroll
    for (int i = 0; i < NBLOCKS / 256; ++i)
        s += partial[threadIdx.x + i * 256];
    sh[threadIdx.x] = s;
    __syncthreads();
    for (int off = 128; off > 0; off >>= 1) {
        if (threadIdx.x < off) sh[threadIdx.x] += sh[threadIdx.x + off];
        __syncthreads();
    }
    if (threadIdx.x == 0)
        out[LOSS_OFF] = 1.25f * sh[0] / (float)OUT_ELEMS;
}

extern "C" void kernel_launch(void* const* d_in, const int* in_sizes, int n_in,
                              void* d_out, int out_size, void* d_ws,
                              size_t ws_size, hipStream_t stream) {
    const float* z  = (const float*)d_in[0];   // [64, 64, 32, 32] f32
    const float* cb = (const float*)d_in[1];   // [512, 64] f32
    float* out = (float*)d_out;
    float* wsf = (float*)d_ws;
    float* e2      = wsf;          // 512 floats
    float* partial = wsf + K;      // 1024 floats

    vq_e2_kernel<<<(K + 255) / 256, 256, 0, stream>>>(cb, e2);
    vq_main_kernel<<<NBLOCKS, 256, 0, stream>>>(z, cb, e2, out, partial);
    vq_loss_kernel<<<1, 256, 0, stream>>>(partial, out);
}

// Round 6
// 58.356 us; speedup vs baseline: 4.1809x; 1.6695x over previous
//
#include <hip/hip_runtime.h>
#include <hip/hip_bf16.h>
#include <float.h>

#define D 64
#define K 512
#define HW 1024
#define DHW (D * HW)
#define N_PTS 65536
#define OUT_ELEMS (64 * D * HW)     /* 4,194,304 */
#define LOSS_OFF OUT_ELEMS
#define IDX_OFF (OUT_ELEMS + 1)
#define PTS_PER_BLOCK 64
#define NBLOCKS (N_PTS / PTS_PER_BLOCK)   /* 1024 */
#define TAUP 4.0e-5f   /* score-space candidate margin (bound ~1e-5, 4x slack) */

typedef unsigned short ushort_t;
typedef __attribute__((ext_vector_type(8))) short bf16x8;
typedef __attribute__((ext_vector_type(4))) float f32x4;

union U16x8 { uint4 u; bf16x8 v; ushort_t s[8]; };

__device__ __forceinline__ ushort_t f2bf(float v) {
    __hip_bfloat16 h = __float2bfloat16(v);
    return *reinterpret_cast<ushort_t*>(&h);
}
__device__ __forceinline__ float bf2f(ushort_t u) {
    unsigned int x = ((unsigned int)u) << 16;
    return *reinterpret_cast<float*>(&x);
}

// ---------------------------------------------------------------------------
// numpy pairwise-sum (n=64): 8 accumulators over squares, combined
// ((r0+r1)+(r2+r3))+((r4+r5)+(r6+r7)); all adds/muls un-contracted.
// ---------------------------------------------------------------------------
__device__ __forceinline__ float np_sumsq64(const float* v) {
    float r[8];
#pragma unroll
    for (int j = 0; j < 8; ++j) r[j] = __fmul_rn(v[j], v[j]);
#pragma unroll
    for (int i = 8; i < D; i += 8) {
#pragma unroll
        for (int j = 0; j < 8; ++j)
            r[j] = __fadd_rn(r[j], __fmul_rn(v[i + j], v[i + j]));
    }
    return __fadd_rn(
        __fadd_rn(__fadd_rn(r[0], r[1]), __fadd_rn(r[2], r[3])),
        __fadd_rn(__fadd_rn(r[4], r[5]), __fadd_rn(r[6], r[7])));
}

// ---------------------------------------------------------------------------
// Kernel 1: ||e_k||^2 in numpy pairwise order -> ws
// ---------------------------------------------------------------------------
__global__ void vq_e2_kernel(const float* __restrict__ cb,
                             float* __restrict__ e2) {
    int k = blockIdx.x * blockDim.x + threadIdx.x;
    if (k < K) {
        float row[D];
#pragma unroll
        for (int d = 0; d < D; ++d) row[d] = cb[k * D + d];
        e2[k] = np_sumsq64(row);
    }
}

// ---------------------------------------------------------------------------
// Kernel 1b: codebook -> bf16 hi/lo B-fragment layout.
// Fragment for MFMA 16x16x32: lane l holds col(code-in-tile)=l&15,
// k = (l>>4)*8 + i (i=0..7).  Storage: uint4[kh][nt][lane] (2*2048 uint4).
// ---------------------------------------------------------------------------
__global__ void vq_frag_kernel(const float* __restrict__ cb,
                               uint4* __restrict__ bhi,
                               uint4* __restrict__ blo) {
    int gid = blockIdx.x * blockDim.x + threadIdx.x;   // 0..4095
    int kh = gid >> 11, r = gid & 2047, nt = r >> 6, l = r & 63;
    int code = nt * 16 + (l & 15);
    int d0   = kh * 32 + ((l >> 4) << 3);
    const float* src = cb + code * D + d0;
    U16x8 hi, lo;
#pragma unroll
    for (int i = 0; i < 8; ++i) {
        float v  = src[i];
        ushort_t h = f2bf(v);
        hi.s[i] = h;
        lo.s[i] = f2bf(__fsub_rn(v, bf2f(h)));
    }
    bhi[gid] = hi.u;
    blo[gid] = lo.u;
}

// ---------------------------------------------------------------------------
// Kernel 2: main VQ via MFMA filter + exact rescore.
// Block = 64 points, 4 waves. Wave w: points [ (w>>1)*32, +32 ), codes
// half (w&1)*256. C tiles: 2 Mt x 16 Nt, f32x4 each (128 VGPR).
// 3 bf16 passes (xh*eh, xl*eh, xh*el) accumulate into C ~= x.e with error
// <= ~1e-6 << fp32 ulp@64 (7.6e-6).  score = C - 0.5*||e||^2; candidates
// score >= max - TAUP are exactly rescored with the numpy-rounding chain
// (validated in rounds 2-5) -> bit-identical idx.
// ---------------------------------------------------------------------------
__global__ __launch_bounds__(256, 2) void vq_main_kernel(
        const float* __restrict__ z, const float* __restrict__ cb,
        const float* __restrict__ e2, const uint4* __restrict__ bhi,
        const uint4* __restrict__ blo, float* __restrict__ out,
        float* __restrict__ partial) {
    __shared__ uint4 b_lds[2048];          // 32KB: current B stage
    __shared__ float x_lds[D][64];         // 16KB [d][point]
    __shared__ float e2_lds[K];
    __shared__ float A_np[64];
    __shared__ float smax[64][2];
    __shared__ float gthr[64];
    __shared__ int   cnt[64];
    __shared__ int   cand[64][4];
    __shared__ int   ids[64];
    __shared__ int   ovf_cnt;
    __shared__ int   ovf_list[64];
    __shared__ float rd_d[256];
    __shared__ int   rd_k[256];
    __shared__ float wsum[4];

    const int t     = threadIdx.x;
    const int l     = t & 63;
    const int w     = t >> 6;
    const int chalf = w & 1;          // code half (0: 0-255, 1: 256-511)
    const int p0    = (w >> 1) * 32;  // wave's point-group base
    const int n0    = blockIdx.x * PTS_PER_BLOCK;
    const int b     = n0 >> 10;
    const int hw0   = n0 & 1023;

    // ---- Phase 0: stage x (coalesced), e2, init ----
    const float* zb = z + b * DHW + hw0;
#pragma unroll
    for (int i = 0; i < 16; ++i) {
        const int d = w * 16 + i;
        x_lds[d][l] = zb[d * HW + l];
    }
    e2_lds[t]       = e2[t];
    e2_lds[t + 256] = e2[t + 256];
    if (t < 64) cnt[t] = 0;
    if (t == 0) ovf_cnt = 0;
    __syncthreads();

    // A_np: numpy-pairwise ||x||^2 for point l (wave 0 only)
    if (w == 0) {
        float r[8];
#pragma unroll
        for (int j = 0; j < 8; ++j) {
            float v = x_lds[j][l];
            r[j] = __fmul_rn(v, v);
        }
#pragma unroll
        for (int d = 8; d < D; ++d) {
            float v = x_lds[d][l];
            r[d & 7] = __fadd_rn(r[d & 7], __fmul_rn(v, v));
        }
        A_np[l] = __fadd_rn(
            __fadd_rn(__fadd_rn(r[0], r[1]), __fadd_rn(r[2], r[3])),
            __fadd_rn(__fadd_rn(r[4], r[5]), __fadd_rn(r[6], r[7])));
    }

    // A-fragments: ah/al[Mt][kh]; lane l: row=l&15 -> point p0+Mt*16+(l&15),
    // k = (l>>4)*8+i -> d = kh*32 + (l>>4)*8 + i.
    bf16x8 ah[2][2], al[2][2];
#pragma unroll
    for (int Mt = 0; Mt < 2; ++Mt) {
#pragma unroll
        for (int kh = 0; kh < 2; ++kh) {
            const int pt = p0 + Mt * 16 + (l & 15);
            const int d0 = kh * 32 + ((l >> 4) << 3);
            U16x8 uh, ul;
#pragma unroll
            for (int i = 0; i < 8; ++i) {
                float v = x_lds[d0 + i][pt];
                ushort_t h = f2bf(v);
                uh.s[i] = h;
                ul.s[i] = f2bf(__fsub_rn(v, bf2f(h)));
            }
            ah[Mt][kh] = uh.v;
            al[Mt][kh] = ul.v;
        }
    }

    // ---- MFMA phases: per kh: stage Bhi -> (hh + lh), stage Blo -> (hl) ----
    f32x4 c[2][16];
#pragma unroll
    for (int Mt = 0; Mt < 2; ++Mt)
#pragma unroll
        for (int nt = 0; nt < 16; ++nt) c[Mt][nt] = (f32x4){0.f, 0.f, 0.f, 0.f};

#pragma unroll
    for (int kh = 0; kh < 2; ++kh) {
        // stage Bhi(kh)
        {
            const uint4* src = bhi + kh * 2048;
#pragma unroll
            for (int i = 0; i < 8; ++i) b_lds[i * 256 + t] = src[i * 256 + t];
        }
        __syncthreads();
#pragma unroll
        for (int ntL = 0; ntL < 16; ++ntL) {
            const int nt = chalf * 16 + ntL;
            U16x8 bu; bu.u = b_lds[nt * 64 + l];
            c[0][ntL] = __builtin_amdgcn_mfma_f32_16x16x32_bf16(ah[0][kh], bu.v, c[0][ntL], 0, 0, 0);
            c[1][ntL] = __builtin_amdgcn_mfma_f32_16x16x32_bf16(ah[1][kh], bu.v, c[1][ntL], 0, 0, 0);
            c[0][ntL] = __builtin_amdgcn_mfma_f32_16x16x32_bf16(al[0][kh], bu.v, c[0][ntL], 0, 0, 0);
            c[1][ntL] = __builtin_amdgcn_mfma_f32_16x16x32_bf16(al[1][kh], bu.v, c[1][ntL], 0, 0, 0);
        }
        __syncthreads();
        // stage Blo(kh)
        {
            const uint4* src = blo + kh * 2048;
#pragma unroll
            for (int i = 0; i < 8; ++i) b_lds[i * 256 + t] = src[i * 256 + t];
        }
        __syncthreads();
#pragma unroll
        for (int ntL = 0; ntL < 16; ++ntL) {
            const int nt = chalf * 16 + ntL;
            U16x8 bu; bu.u = b_lds[nt * 64 + l];
            c[0][ntL] = __builtin_amdgcn_mfma_f32_16x16x32_bf16(ah[0][kh], bu.v, c[0][ntL], 0, 0, 0);
            c[1][ntL] = __builtin_amdgcn_mfma_f32_16x16x32_bf16(ah[1][kh], bu.v, c[1][ntL], 0, 0, 0);
        }
        __syncthreads();
    }

    // ---- Pass 1: per-point max of score = C - 0.5*B (C/D: col=l&15,
    // row=(l>>4)*4+reg; point = p0 + Mt*16 + row; code = chalf*256+nt*16+col)
    float rmax[2][4];
#pragma unroll
    for (int Mt = 0; Mt < 2; ++Mt)
#pragma unroll
        for (int r = 0; r < 4; ++r) rmax[Mt][r] = -FLT_MAX;
#pragma unroll
    for (int ntL = 0; ntL < 16; ++ntL) {
        const float B = e2_lds[chalf * 256 + ntL * 16 + (l & 15)];
#pragma unroll
        for (int Mt = 0; Mt < 2; ++Mt)
#pragma unroll
            for (int r = 0; r < 4; ++r) {
                float s = __builtin_fmaf(B, -0.5f, c[Mt][ntL][r]);
                rmax[Mt][r] = fmaxf(rmax[Mt][r], s);
            }
    }
#pragma unroll
    for (int mask = 1; mask < 16; mask <<= 1)
#pragma unroll
        for (int Mt = 0; Mt < 2; ++Mt)
#pragma unroll
            for (int r = 0; r < 4; ++r)
                rmax[Mt][r] = fmaxf(rmax[Mt][r], __shfl_xor(rmax[Mt][r], mask));
    if ((l & 15) == 0) {
#pragma unroll
        for (int Mt = 0; Mt < 2; ++Mt)
#pragma unroll
            for (int r = 0; r < 4; ++r)
                smax[p0 + Mt * 16 + (l >> 4) * 4 + r][chalf] = rmax[Mt][r];
    }
    __syncthreads();
    if (t < 64) gthr[t] = fmaxf(smax[t][0], smax[t][1]) - TAUP;
    __syncthreads();

    // ---- Pass 2: collect candidates ----
    float thr[2][4];
#pragma unroll
    for (int Mt = 0; Mt < 2; ++Mt)
#pragma unroll
        for (int r = 0; r < 4; ++r)
            thr[Mt][r] = gthr[p0 + Mt * 16 + (l >> 4) * 4 + r];
#pragma unroll
    for (int ntL = 0; ntL < 16; ++ntL) {
        const float B = e2_lds[chalf * 256 + ntL * 16 + (l & 15)];
#pragma unroll
        for (int Mt = 0; Mt < 2; ++Mt)
#pragma unroll
            for (int r = 0; r < 4; ++r) {
                float s = __builtin_fmaf(B, -0.5f, c[Mt][ntL][r]);
                if (s >= thr[Mt][r]) {
                    int p = p0 + Mt * 16 + (l >> 4) * 4 + r;
                    int slot = atomicAdd(&cnt[p], 1);
                    if (slot < 4)
                        cand[p][slot] = chalf * 256 + ntL * 16 + (l & 15);
                }
            }
    }
    __syncthreads();

    // ---- Rescore: exact numpy-rounding chain on candidates ----
    if (t < 64) {
        int c_ = cnt[t];
        int best = -1;
        if (c_ == 1) {
            best = cand[t][0];
        } else if (c_ <= 4) {
            float bd = FLT_MAX; int bk = 1 << 30;
            for (int s = 0; s < 4; ++s) {
                if (s < c_) {
                    int k = cand[t][s];
                    float acc = 0.f;
                    for (int d = 0; d < D; ++d)
                        acc = __builtin_fmaf(x_lds[d][t], cb[k * D + d], acc);
                    float dist = __fsub_rn(__fadd_rn(A_np[t], e2_lds[k]),
                                           2.0f * acc);
                    if (dist < bd || (dist == bd && k < bk)) { bd = dist; bk = k; }
                }
            }
            best = bk;
        } else {
            int o = atomicAdd(&ovf_cnt, 1);
            ovf_list[o] = t;
        }
        if (best >= 0) {
            ids[t] = best;
            out[IDX_OFF + n0 + t] = (float)best;
        }
    }
    __syncthreads();

    // ---- Overflow fallback (block-uniform; essentially never runs) ----
    const int novf = ovf_cnt;
    for (int oi = 0; oi < novf; ++oi) {
        const int p = ovf_list[oi];
        float bd = FLT_MAX; int bk = 1 << 30;
#pragma unroll
        for (int half = 0; half < 2; ++half) {
            int k = t + half * 256;
            float acc = 0.f;
            for (int d = 0; d < D; ++d)
                acc = __builtin_fmaf(x_lds[d][p], cb[k * D + d], acc);
            float dist = __fsub_rn(__fadd_rn(A_np[p], e2_lds[k]), 2.0f * acc);
            if (dist < bd || (dist == bd && k < bk)) { bd = dist; bk = k; }
        }
        rd_d[t] = bd; rd_k[t] = bk;
        __syncthreads();
        for (int off = 128; off > 0; off >>= 1) {
            if (t < off) {
                float od = rd_d[t + off]; int ok = rd_k[t + off];
                if (od < rd_d[t] || (od == rd_d[t] && ok < rd_k[t])) {
                    rd_d[t] = od; rd_k[t] = ok;
                }
            }
            __syncthreads();
        }
        if (t == 0) {
            ids[p] = rd_k[0];
            out[IDX_OFF + n0 + p] = (float)rd_k[0];
        }
        __syncthreads();
    }
    __syncthreads();

    // ---- Epilogue: out = fl(x + fl(q - x)), loss partials ----
    float* ob = out + b * DHW + hw0;
    const int myid = ids[l];
    float lsum = 0.f;
#pragma unroll
    for (int i = 0; i < 16; ++i) {
        const int d  = w * 16 + i;
        const float xv   = x_lds[d][l];
        const float q    = cb[myid * D + d];
        const float diff = __fsub_rn(q, xv);
        lsum = __builtin_fmaf(diff, diff, lsum);
        ob[d * HW + l] = __fadd_rn(xv, diff);
    }
#pragma unroll
    for (int off = 32; off > 0; off >>= 1) lsum += __shfl_down(lsum, off);
    if (l == 0) wsum[w] = lsum;
    __syncthreads();
    if (t == 0)
        partial[blockIdx.x] = __fadd_rn(__fadd_rn(wsum[0], wsum[1]),
                                        __fadd_rn(wsum[2], wsum[3]));
}

// ---------------------------------------------------------------------------
// Kernel 3: reduce 1024 block partials -> loss = 1.25 * MSE
// ---------------------------------------------------------------------------
__global__ void vq_loss_kernel(const float* __restrict__ partial,
                               float* __restrict__ out) {
    __shared__ float sh[256];
    float s = 0.f;
#pragma unroll
    for (int i = 0; i < NBLOCKS / 256; ++i)
        s += partial[threadIdx.x + i * 256];
    sh[threadIdx.x] = s;
    __syncthreads();
    for (int off = 128; off > 0; off >>= 1) {
        if (threadIdx.x < off) sh[threadIdx.x] += sh[threadIdx.x + off];
        __syncthreads();
    }
    if (threadIdx.x == 0)
        out[LOSS_OFF] = 1.25f * sh[0] / (float)OUT_ELEMS;
}

extern "C" void kernel_launch(void* const* d_in, const int* in_sizes, int n_in,
                              void* d_out, int out_size, void* d_ws,
                              size_t ws_size, hipStream_t stream) {
    const float* z  = (const float*)d_in[0];   // [64, 64, 32, 32] f32
    const float* cb = (const float*)d_in[1];   // [512, 64] f32
    float* out = (float*)d_out;
    float* wsf = (float*)d_ws;
    float* e2      = wsf;                      // 512 f32
    float* partial = wsf + 512;                // 1024 f32
    uint4* bhi     = (uint4*)(wsf + 2048);     // 4096 uint4 = 64KB
    uint4* blo     = bhi + 4096;               // 64KB

    vq_e2_kernel<<<2, 256, 0, stream>>>(cb, e2);
    vq_frag_kernel<<<16, 256, 0, stream>>>(cb, bhi, blo);
    vq_main_kernel<<<NBLOCKS, 256, 0, stream>>>(z, cb, e2, bhi, blo, out, partial);
    vq_loss_kernel<<<1, 256, 0, stream>>>(partial, out);
}

// Round 7
// 45.856 us; speedup vs baseline: 5.3206x; 1.2726x over previous
//
#include <hip/hip_runtime.h>
#include <hip/hip_bf16.h>
#include <float.h>

#define D 64
#define K 512
#define HW 1024
#define DHW (D * HW)
#define N_PTS 65536
#define OUT_ELEMS (64 * D * HW)     /* 4,194,304 */
#define LOSS_OFF OUT_ELEMS
#define IDX_OFF (OUT_ELEMS + 1)
#define PTS_PER_BLOCK 64
#define NBLOCKS (N_PTS / PTS_PER_BLOCK)   /* 1024 */

typedef unsigned short ushort_t;
typedef __attribute__((ext_vector_type(8))) short bf16x8;
typedef __attribute__((ext_vector_type(4))) float f32x4;

union U16x8 { uint4 u; bf16x8 v; ushort_t s[8]; };

__device__ __forceinline__ ushort_t f2bf(float v) {
    __hip_bfloat16 h = __float2bfloat16(v);
    return *reinterpret_cast<ushort_t*>(&h);
}
__device__ __forceinline__ float bf2f(ushort_t u) {
    unsigned int x = ((unsigned int)u) << 16;
    return *reinterpret_cast<float*>(&x);
}

// ---------------------------------------------------------------------------
// numpy pairwise-sum (n=64): 8 accumulators over squares, combined
// ((r0+r1)+(r2+r3))+((r4+r5)+(r6+r7)); all adds/muls un-contracted.
// ---------------------------------------------------------------------------
__device__ __forceinline__ float np_sumsq64(const float* v) {
    float r[8];
#pragma unroll
    for (int j = 0; j < 8; ++j) r[j] = __fmul_rn(v[j], v[j]);
#pragma unroll
    for (int i = 8; i < D; i += 8) {
#pragma unroll
        for (int j = 0; j < 8; ++j)
            r[j] = __fadd_rn(r[j], __fmul_rn(v[i + j], v[i + j]));
    }
    return __fadd_rn(
        __fadd_rn(__fadd_rn(r[0], r[1]), __fadd_rn(r[2], r[3])),
        __fadd_rn(__fadd_rn(r[4], r[5]), __fadd_rn(r[6], r[7])));
}

// ---------------------------------------------------------------------------
// Prep kernel (2 blocks x 256): thread = code k.
//  - e2[k]  : ||e_k||^2 in numpy pairwise order
//  - bhi    : bf16(hi) B-fragments, layout verified in round 6:
//             gid = kh*2048 + (k>>4)*64 + g*16 + (k&15), g = k-slice (l>>4)
//  - mpart[b]: block max of |e - bf16(e)|  (for the rigorous x.e_lo bound)
// ---------------------------------------------------------------------------
__global__ void vq_prep_kernel(const float* __restrict__ cb,
                               float* __restrict__ e2,
                               uint4* __restrict__ bhi,
                               float* __restrict__ mpart) {
    __shared__ float mred[256];
    const int k = blockIdx.x * 256 + threadIdx.x;
    float row[D];
#pragma unroll
    for (int d = 0; d < D; ++d) row[d] = cb[k * D + d];
    e2[k] = np_sumsq64(row);

    float mmax = 0.f;
#pragma unroll
    for (int kh = 0; kh < 2; ++kh) {
#pragma unroll
        for (int g = 0; g < 4; ++g) {
            U16x8 u;
#pragma unroll
            for (int i = 0; i < 8; ++i) {
                float v = row[kh * 32 + g * 8 + i];
                ushort_t h = f2bf(v);
                u.s[i] = h;
                mmax = fmaxf(mmax, fabsf(__fsub_rn(v, bf2f(h))));
            }
            bhi[kh * 2048 + (k >> 4) * 64 + g * 16 + (k & 15)] = u.u;
        }
    }
    mred[threadIdx.x] = mmax;
    __syncthreads();
    for (int off = 128; off > 0; off >>= 1) {
        if (threadIdx.x < off)
            mred[threadIdx.x] = fmaxf(mred[threadIdx.x], mred[threadIdx.x + off]);
        __syncthreads();
    }
    if (threadIdx.x == 0) mpart[blockIdx.x] = mred[0];
}

// ---------------------------------------------------------------------------
// Main VQ: MFMA filter + exact rescore. Block = 64 points, 4 waves.
// Wave w: points [(w>>1)*32, +32), code half (w&1)*256.
// M_hat = (xh + xl) . eh via 2 MFMA passes sharing one B load (4 MFMA/load,
// B straight from global/L2 — no LDS staging, no stage barriers).
// Residual x.e_lo bounded rigorously per point: |x.el| <= sum|x_d| * M_EL.
// Candidates score >= max - (4e-5 + 2*sum|x|*M_EL) exactly rescored with the
// bit-exact numpy chain (validated rounds 2-6); >4 candidates -> full scan.
// ---------------------------------------------------------------------------
__global__ __launch_bounds__(256, 2) void vq_main_kernel(
        const float* __restrict__ z, const float* __restrict__ cb,
        const float* __restrict__ e2, const uint4* __restrict__ bhi,
        const float* __restrict__ mpart, float* __restrict__ out,
        float* __restrict__ partial) {
    __shared__ float x_lds[D][65];         // pad 65: conflict-free reads
    __shared__ float e2_lds[K];
    __shared__ float A_np[64];
    __shared__ float sabs[64];
    __shared__ float smax[64][2];
    __shared__ float gthr[64];
    __shared__ int   cnt[64];
    __shared__ int   cand[64][4];
    __shared__ int   ids[64];
    __shared__ int   ovf_cnt;
    __shared__ int   ovf_list[64];
    __shared__ float rd_d[256];
    __shared__ int   rd_k[256];
    __shared__ float wsum[4];

    const int t     = threadIdx.x;
    const int l     = t & 63;
    const int w     = t >> 6;
    const int chalf = w & 1;
    const int p0    = (w >> 1) * 32;
    const int n0    = blockIdx.x * PTS_PER_BLOCK;
    const int b     = n0 >> 10;
    const int hw0   = n0 & 1023;

    const float M_EL = fmaxf(mpart[0], mpart[1]);

    // ---- stage x (coalesced), e2, init ----
    const float* zb = z + b * DHW + hw0;
#pragma unroll
    for (int i = 0; i < 16; ++i) {
        const int d = w * 16 + i;
        x_lds[d][l] = zb[d * HW + l];
    }
    e2_lds[t]       = e2[t];
    e2_lds[t + 256] = e2[t + 256];
    if (t < 64) cnt[t] = 0;
    if (t == 0) ovf_cnt = 0;
    __syncthreads();

    // wave 0: numpy-pairwise ||x||^2 and sum|x| per point (runs concurrent
    // with other waves' fragment build; consumed after later barriers)
    if (w == 0) {
        float r[8];
        float sa = 0.f;
#pragma unroll
        for (int j = 0; j < 8; ++j) {
            float v = x_lds[j][l];
            r[j] = __fmul_rn(v, v);
            sa += fabsf(v);
        }
#pragma unroll
        for (int d = 8; d < D; ++d) {
            float v = x_lds[d][l];
            r[d & 7] = __fadd_rn(r[d & 7], __fmul_rn(v, v));
            sa += fabsf(v);
        }
        A_np[l] = __fadd_rn(
            __fadd_rn(__fadd_rn(r[0], r[1]), __fadd_rn(r[2], r[3])),
            __fadd_rn(__fadd_rn(r[4], r[5]), __fadd_rn(r[6], r[7])));
        sabs[l] = sa;
    }

    // ---- A fragments (hi + exact lo residual), layout verified round 6 ----
    bf16x8 ah[2][2], al[2][2];
#pragma unroll
    for (int Mt = 0; Mt < 2; ++Mt) {
#pragma unroll
        for (int kh = 0; kh < 2; ++kh) {
            const int pt = p0 + Mt * 16 + (l & 15);
            const int d0 = kh * 32 + ((l >> 4) << 3);
            U16x8 uh, ul;
#pragma unroll
            for (int i = 0; i < 8; ++i) {
                float v = x_lds[d0 + i][pt];
                ushort_t h = f2bf(v);
                uh.s[i] = h;
                ul.s[i] = f2bf(__fsub_rn(v, bf2f(h)));
            }
            ah[Mt][kh] = uh.v;
            al[Mt][kh] = ul.v;
        }
    }

    // ---- MFMA: C = (xh + xl) . eh ; B per-lane from global (L2-hot) ----
    f32x4 c[2][16];
#pragma unroll
    for (int Mt = 0; Mt < 2; ++Mt)
#pragma unroll
        for (int nt = 0; nt < 16; ++nt) c[Mt][nt] = (f32x4){0.f, 0.f, 0.f, 0.f};

#pragma unroll
    for (int kh = 0; kh < 2; ++kh) {
#pragma unroll
        for (int ntL = 0; ntL < 16; ++ntL) {
            U16x8 bu;
            bu.u = bhi[kh * 2048 + (chalf * 16 + ntL) * 64 + l];
            c[0][ntL] = __builtin_amdgcn_mfma_f32_16x16x32_bf16(ah[0][kh], bu.v, c[0][ntL], 0, 0, 0);
            c[1][ntL] = __builtin_amdgcn_mfma_f32_16x16x32_bf16(ah[1][kh], bu.v, c[1][ntL], 0, 0, 0);
            c[0][ntL] = __builtin_amdgcn_mfma_f32_16x16x32_bf16(al[0][kh], bu.v, c[0][ntL], 0, 0, 0);
            c[1][ntL] = __builtin_amdgcn_mfma_f32_16x16x32_bf16(al[1][kh], bu.v, c[1][ntL], 0, 0, 0);
        }
    }

    // ---- pass 1: per-point max of score = C - 0.5*||e||^2 ----
    float rmax[2][4];
#pragma unroll
    for (int Mt = 0; Mt < 2; ++Mt)
#pragma unroll
        for (int r = 0; r < 4; ++r) rmax[Mt][r] = -FLT_MAX;
#pragma unroll
    for (int ntL = 0; ntL < 16; ++ntL) {
        const float B = e2_lds[chalf * 256 + ntL * 16 + (l & 15)];
#pragma unroll
        for (int Mt = 0; Mt < 2; ++Mt)
#pragma unroll
            for (int r = 0; r < 4; ++r) {
                float s = __builtin_fmaf(B, -0.5f, c[Mt][ntL][r]);
                rmax[Mt][r] = fmaxf(rmax[Mt][r], s);
            }
    }
#pragma unroll
    for (int mask = 1; mask < 16; mask <<= 1)
#pragma unroll
        for (int Mt = 0; Mt < 2; ++Mt)
#pragma unroll
            for (int r = 0; r < 4; ++r)
                rmax[Mt][r] = fmaxf(rmax[Mt][r], __shfl_xor(rmax[Mt][r], mask));
    if ((l & 15) == 0) {
#pragma unroll
        for (int Mt = 0; Mt < 2; ++Mt)
#pragma unroll
            for (int r = 0; r < 4; ++r)
                smax[p0 + Mt * 16 + (l >> 4) * 4 + r][chalf] = rmax[Mt][r];
    }
    __syncthreads();
    if (t < 64)
        gthr[t] = fmaxf(smax[t][0], smax[t][1])
                  - (4.0e-5f + 2.0f * sabs[t] * M_EL);   // rigorous margin
    __syncthreads();

    // ---- pass 2: collect candidates ----
    float thr[2][4];
#pragma unroll
    for (int Mt = 0; Mt < 2; ++Mt)
#pragma unroll
        for (int r = 0; r < 4; ++r)
            thr[Mt][r] = gthr[p0 + Mt * 16 + (l >> 4) * 4 + r];
#pragma unroll
    for (int ntL = 0; ntL < 16; ++ntL) {
        const float B = e2_lds[chalf * 256 + ntL * 16 + (l & 15)];
#pragma unroll
        for (int Mt = 0; Mt < 2; ++Mt)
#pragma unroll
            for (int r = 0; r < 4; ++r) {
                float s = __builtin_fmaf(B, -0.5f, c[Mt][ntL][r]);
                if (s >= thr[Mt][r]) {
                    int p = p0 + Mt * 16 + (l >> 4) * 4 + r;
                    int slot = atomicAdd(&cnt[p], 1);
                    if (slot < 4)
                        cand[p][slot] = chalf * 256 + ntL * 16 + (l & 15);
                }
            }
    }
    __syncthreads();

    // ---- exact rescore (bit-exact numpy chain, rounds 2-6 validated) ----
    if (t < 64) {
        int c_ = cnt[t];
        int best = -1;
        if (c_ == 1) {
            best = cand[t][0];
        } else if (c_ <= 4) {
            float bd = FLT_MAX; int bk = 1 << 30;
            for (int s = 0; s < 4; ++s) {
                if (s < c_) {
                    int k = cand[t][s];
                    float acc = 0.f;
                    for (int d = 0; d < D; ++d)
                        acc = __builtin_fmaf(x_lds[d][t], cb[k * D + d], acc);
                    float dist = __fsub_rn(__fadd_rn(A_np[t], e2_lds[k]),
                                           2.0f * acc);
                    if (dist < bd || (dist == bd && k < bk)) { bd = dist; bk = k; }
                }
            }
            best = bk;
        } else {
            int o = atomicAdd(&ovf_cnt, 1);
            ovf_list[o] = t;
        }
        if (best >= 0) {
            ids[t] = best;
            out[IDX_OFF + n0 + t] = (float)best;
        }
    }
    __syncthreads();

    // ---- overflow fallback (block-uniform; essentially never runs) ----
    const int novf = ovf_cnt;
    for (int oi = 0; oi < novf; ++oi) {
        const int p = ovf_list[oi];
        float bd = FLT_MAX; int bk = 1 << 30;
#pragma unroll
        for (int half = 0; half < 2; ++half) {
            int k = t + half * 256;
            float acc = 0.f;
            for (int d = 0; d < D; ++d)
                acc = __builtin_fmaf(x_lds[d][p], cb[k * D + d], acc);
            float dist = __fsub_rn(__fadd_rn(A_np[p], e2_lds[k]), 2.0f * acc);
            if (dist < bd || (dist == bd && k < bk)) { bd = dist; bk = k; }
        }
        rd_d[t] = bd; rd_k[t] = bk;
        __syncthreads();
        for (int off = 128; off > 0; off >>= 1) {
            if (t < off) {
                float od = rd_d[t + off]; int ok = rd_k[t + off];
                if (od < rd_d[t] || (od == rd_d[t] && ok < rd_k[t])) {
                    rd_d[t] = od; rd_k[t] = ok;
                }
            }
            __syncthreads();
        }
        if (t == 0) {
            ids[p] = rd_k[0];
            out[IDX_OFF + n0 + p] = (float)rd_k[0];
        }
        __syncthreads();
    }
    __syncthreads();

    // ---- epilogue: out = fl(x + fl(q - x)), loss partials ----
    float* ob = out + b * DHW + hw0;
    const int myid = ids[l];
    float lsum = 0.f;
#pragma unroll
    for (int i = 0; i < 16; ++i) {
        const int d  = w * 16 + i;
        const float xv   = x_lds[d][l];
        const float q    = cb[myid * D + d];
        const float diff = __fsub_rn(q, xv);
        lsum = __builtin_fmaf(diff, diff, lsum);
        ob[d * HW + l] = __fadd_rn(xv, diff);
    }
#pragma unroll
    for (int off = 32; off > 0; off >>= 1) lsum += __shfl_down(lsum, off);
    if (l == 0) wsum[w] = lsum;
    __syncthreads();
    if (t == 0)
        partial[blockIdx.x] = __fadd_rn(__fadd_rn(wsum[0], wsum[1]),
                                        __fadd_rn(wsum[2], wsum[3]));
}

// ---------------------------------------------------------------------------
// Loss kernel: reduce 1024 block partials -> loss = 1.25 * MSE
// ---------------------------------------------------------------------------
__global__ void vq_loss_kernel(const float* __restrict__ partial,
                               float* __restrict__ out) {
    __shared__ float sh[256];
    float s = 0.f;
#pragma unroll
    for (int i = 0; i < NBLOCKS / 256; ++i)
        s += partial[threadIdx.x + i * 256];
    sh[threadIdx.x] = s;
    __syncthreads();
    for (int off = 128; off > 0; off >>= 1) {
        if (threadIdx.x < off) sh[threadIdx.x] += sh[threadIdx.x + off];
        __syncthreads();
    }
    if (threadIdx.x == 0)
        out[LOSS_OFF] = 1.25f * sh[0] / (float)OUT_ELEMS;
}

extern "C" void kernel_launch(void* const* d_in, const int* in_sizes, int n_in,
                              void* d_out, int out_size, void* d_ws,
                              size_t ws_size, hipStream_t stream) {
    const float* z  = (const float*)d_in[0];   // [64, 64, 32, 32] f32
    const float* cb = (const float*)d_in[1];   // [512, 64] f32
    float* out = (float*)d_out;
    float* wsf = (float*)d_ws;
    float* e2      = wsf;                      // 512 f32
    float* partial = wsf + 512;                // 1024 f32
    float* mpart   = wsf + 1536;               // 2 f32
    uint4* bhi     = (uint4*)(wsf + 2048);     // 4096 uint4 = 64KB

    vq_prep_kernel<<<2, 256, 0, stream>>>(cb, e2, bhi, mpart);
    vq_main_kernel<<<NBLOCKS, 256, 0, stream>>>(z, cb, e2, bhi, mpart, out, partial);
    vq_loss_kernel<<<1, 256, 0, stream>>>(partial, out);
}